// Round 1
// baseline (462.306 us; speedup 1.0000x reference)
//
#include <hip/hip_runtime.h>
#include <math.h>

#define NROW 65536      // I*J = 256*256
#define INF_ 1.0e9f
#define LN_EPS_ 1e-5f

// ---------------------------------------------------------------------------
// Kernel 1: LayerNorm over C=128 per row + tri bias (xn . tri_w -> [H][I][J])
// One wave (64 lanes) per row; 4 rows per 256-thread block.
// ---------------------------------------------------------------------------
__global__ __launch_bounds__(256) void ln_tri_kernel(
    const float* __restrict__ x, const float* __restrict__ ln_w,
    const float* __restrict__ ln_b, const float* __restrict__ tri_w,
    float* __restrict__ xn, float* __restrict__ tri)
{
    int row  = (blockIdx.x * 256 + threadIdx.x) >> 6;
    int lane = threadIdx.x & 63;

    const float* xr = x + (size_t)row * 128;
    float2 xv = *(const float2*)(xr + lane * 2);

    // pass 1: mean
    float s = xv.x + xv.y;
    #pragma unroll
    for (int m = 32; m >= 1; m >>= 1) s += __shfl_xor(s, m, 64);
    float mu = s * (1.0f / 128.0f);

    // pass 2: variance (mean of squared deviations, matching reference)
    float d0 = xv.x - mu, d1 = xv.y - mu;
    float sq = d0 * d0 + d1 * d1;
    #pragma unroll
    for (int m = 32; m >= 1; m >>= 1) sq += __shfl_xor(sq, m, 64);
    float rstd = rsqrtf(sq * (1.0f / 128.0f) + LN_EPS_);

    float2 wv = *(const float2*)(ln_w + lane * 2);
    float2 bv = *(const float2*)(ln_b + lane * 2);
    float n0 = d0 * rstd * wv.x + bv.x;
    float n1 = d1 * rstd * wv.y + bv.y;
    *(float2*)(xn + (size_t)row * 128 + lane * 2) = make_float2(n0, n1);

    // tri partials: tri_w is [C=128][H=4] row-major
    float4 t0 = *(const float4*)(tri_w + (lane * 2) * 4);
    float4 t1 = *(const float4*)(tri_w + (lane * 2 + 1) * 4);
    float ax = n0 * t0.x + n1 * t1.x;
    float ay = n0 * t0.y + n1 * t1.y;
    float az = n0 * t0.z + n1 * t1.z;
    float aw = n0 * t0.w + n1 * t1.w;
    #pragma unroll
    for (int m = 32; m >= 1; m >>= 1) {
        ax += __shfl_xor(ax, m, 64);
        ay += __shfl_xor(ay, m, 64);
        az += __shfl_xor(az, m, 64);
        aw += __shfl_xor(aw, m, 64);
    }
    if (lane < 4) {
        float v = (lane == 0) ? ax : (lane == 1) ? ay : (lane == 2) ? az : aw;
        tri[(size_t)lane * NROW + row] = v;   // layout [h][i*256+j]
    }
}

// ---------------------------------------------------------------------------
// Kernel 2: fp32 GEMM  C[M,128] = A[M,128] @ W[128,128]  (+epilogue)
// Block: 256 threads, 64x64 output tile. K=128 fully staged in LDS.
// mode 0: none   1: *scale   2: sigmoid(x + bias[col])   3: + bias[col]
// ---------------------------------------------------------------------------
__global__ __launch_bounds__(256) void gemm128_kernel(
    const float* __restrict__ A, const float* __restrict__ W,
    const float* __restrict__ bias, float* __restrict__ C,
    int mode, float scale)
{
    __shared__ float As[128 * 65];   // transposed, +1 pad: As[k*65 + r]
    __shared__ float Bs[128 * 64];   // Bs[k*64 + n]

    int m0 = blockIdx.x * 64;
    int n0 = blockIdx.y * 64;
    int tid = threadIdx.x;

    // stage A tile (64 rows x 128 k), coalesced read, transposed write
    #pragma unroll 8
    for (int it = 0; it < 32; ++it) {
        int idx = it * 256 + tid;
        int r = idx >> 7;        // 0..63
        int kk = idx & 127;
        As[kk * 65 + r] = A[(size_t)(m0 + r) * 128 + kk];
    }
    // stage B tile (128 k x 64 n)
    #pragma unroll 8
    for (int it = 0; it < 32; ++it) {
        int idx = it * 256 + tid;
        int kk = idx >> 6;
        int n = idx & 63;
        Bs[kk * 64 + n] = W[(size_t)kk * 128 + n0 + n];
    }
    __syncthreads();

    int tx = tid & 15;    // col group: cols tx*4 .. +3
    int ty = tid >> 4;    // row group: rows ty*4 .. +3

    float acc[4][4];
    #pragma unroll
    for (int i = 0; i < 4; ++i)
        #pragma unroll
        for (int j = 0; j < 4; ++j) acc[i][j] = 0.0f;

    #pragma unroll 8
    for (int kk = 0; kk < 128; ++kk) {
        float a0 = As[kk * 65 + ty * 4 + 0];
        float a1 = As[kk * 65 + ty * 4 + 1];
        float a2 = As[kk * 65 + ty * 4 + 2];
        float a3 = As[kk * 65 + ty * 4 + 3];
        float4 b = *(const float4*)(Bs + kk * 64 + tx * 4);
        acc[0][0] = fmaf(a0, b.x, acc[0][0]);
        acc[0][1] = fmaf(a0, b.y, acc[0][1]);
        acc[0][2] = fmaf(a0, b.z, acc[0][2]);
        acc[0][3] = fmaf(a0, b.w, acc[0][3]);
        acc[1][0] = fmaf(a1, b.x, acc[1][0]);
        acc[1][1] = fmaf(a1, b.y, acc[1][1]);
        acc[1][2] = fmaf(a1, b.z, acc[1][2]);
        acc[1][3] = fmaf(a1, b.w, acc[1][3]);
        acc[2][0] = fmaf(a2, b.x, acc[2][0]);
        acc[2][1] = fmaf(a2, b.y, acc[2][1]);
        acc[2][2] = fmaf(a2, b.z, acc[2][2]);
        acc[2][3] = fmaf(a2, b.w, acc[2][3]);
        acc[3][0] = fmaf(a3, b.x, acc[3][0]);
        acc[3][1] = fmaf(a3, b.y, acc[3][1]);
        acc[3][2] = fmaf(a3, b.z, acc[3][2]);
        acc[3][3] = fmaf(a3, b.w, acc[3][3]);
    }

    int col = n0 + tx * 4;
    float4 bv = make_float4(0.f, 0.f, 0.f, 0.f);
    if (mode == 2 || mode == 3) bv = *(const float4*)(bias + col);

    #pragma unroll
    for (int i = 0; i < 4; ++i) {
        int row = m0 + ty * 4 + i;
        float4 r = make_float4(acc[i][0], acc[i][1], acc[i][2], acc[i][3]);
        if (mode == 1) {
            r.x *= scale; r.y *= scale; r.z *= scale; r.w *= scale;
        } else if (mode == 2) {
            r.x = 1.0f / (1.0f + __expf(-(r.x + bv.x)));
            r.y = 1.0f / (1.0f + __expf(-(r.y + bv.y)));
            r.z = 1.0f / (1.0f + __expf(-(r.z + bv.z)));
            r.w = 1.0f / (1.0f + __expf(-(r.w + bv.w)));
        } else if (mode == 3) {
            r.x += bv.x; r.y += bv.y; r.z += bv.z; r.w += bv.w;
        }
        *(float4*)(C + (size_t)row * 128 + col) = r;
    }
}

// ---------------------------------------------------------------------------
// Kernel 3: attention per (i,h). Block = 256 threads, thread owns q-row j.
// K/V staged in LDS (broadcast reads). Online softmax in k-tiles of 16.
// Epilogue: gate with sigmoid-g and write og.
// ---------------------------------------------------------------------------
__global__ __launch_bounds__(256) void attn_kernel(
    const float* __restrict__ q, const float* __restrict__ k,
    const float* __restrict__ v, const float* __restrict__ g,
    const float* __restrict__ mask, const float* __restrict__ tri,
    float* __restrict__ og)
{
    __shared__ float Ks[256 * 32];
    __shared__ float Vs[256 * 32];
    __shared__ float mb[256];

    int i = blockIdx.x;
    int h = blockIdx.y;
    int tid = threadIdx.x;
    size_t base = (size_t)i * 256 * 128 + h * 32;   // + j*128 + d

    #pragma unroll 8
    for (int it = 0; it < 32; ++it) {
        int idx = it * 256 + tid;
        int j = idx >> 5, d = idx & 31;
        Ks[idx] = k[base + (size_t)j * 128 + d];
        Vs[idx] = v[base + (size_t)j * 128 + d];
    }
    mb[tid] = INF_ * (mask[i * 256 + tid] - 1.0f);

    // load this thread's q row (pre-scaled by D^-0.5 in proj)
    float qv[32];
    #pragma unroll
    for (int d4 = 0; d4 < 8; ++d4) {
        float4 t = *(const float4*)(q + base + (size_t)tid * 128 + d4 * 4);
        qv[d4 * 4 + 0] = t.x; qv[d4 * 4 + 1] = t.y;
        qv[d4 * 4 + 2] = t.z; qv[d4 * 4 + 3] = t.w;
    }
    __syncthreads();

    const float4* triP = (const float4*)(tri + (size_t)h * NROW + (size_t)tid * 256);

    float m = -3.0e38f, l = 0.0f;
    float o[32];
    #pragma unroll
    for (int d = 0; d < 32; ++d) o[d] = 0.0f;

    for (int kk0 = 0; kk0 < 256; kk0 += 16) {
        // tri bias for this q-row, 16 values
        float tr[16];
        #pragma unroll
        for (int t4 = 0; t4 < 4; ++t4) {
            float4 tv = triP[kk0 / 4 + t4];
            tr[t4 * 4 + 0] = tv.x; tr[t4 * 4 + 1] = tv.y;
            tr[t4 * 4 + 2] = tv.z; tr[t4 * 4 + 3] = tv.w;
        }
        float s[16];
        #pragma unroll
        for (int jt = 0; jt < 16; ++jt) {
            const float* kr = Ks + (kk0 + jt) * 32;
            float a0 = 0.f, a1 = 0.f, a2 = 0.f, a3 = 0.f;
            #pragma unroll
            for (int d = 0; d < 32; d += 4) {
                a0 = fmaf(qv[d + 0], kr[d + 0], a0);
                a1 = fmaf(qv[d + 1], kr[d + 1], a1);
                a2 = fmaf(qv[d + 2], kr[d + 2], a2);
                a3 = fmaf(qv[d + 3], kr[d + 3], a3);
            }
            s[jt] = (a0 + a1) + (a2 + a3) + mb[kk0 + jt] + tr[jt];
        }
        float tm = s[0];
        #pragma unroll
        for (int jt = 1; jt < 16; ++jt) tm = fmaxf(tm, s[jt]);
        float mn = fmaxf(m, tm);
        float corr = __expf(m - mn);
        m = mn;
        float ps = 0.f;
        float p[16];
        #pragma unroll
        for (int jt = 0; jt < 16; ++jt) { p[jt] = __expf(s[jt] - mn); ps += p[jt]; }
        l = l * corr + ps;
        #pragma unroll
        for (int d = 0; d < 32; ++d) o[d] *= corr;
        #pragma unroll
        for (int jt = 0; jt < 16; ++jt) {
            const float* vr = Vs + (kk0 + jt) * 32;
            #pragma unroll
            for (int d = 0; d < 32; ++d) o[d] = fmaf(p[jt], vr[d], o[d]);
        }
    }

    float inv = 1.0f / l;
    #pragma unroll
    for (int d4 = 0; d4 < 8; ++d4) {
        float4 gv = *(const float4*)(g + base + (size_t)tid * 128 + d4 * 4);
        float4 r;
        r.x = o[d4 * 4 + 0] * inv * gv.x;
        r.y = o[d4 * 4 + 1] * inv * gv.y;
        r.z = o[d4 * 4 + 2] * inv * gv.z;
        r.w = o[d4 * 4 + 3] * inv * gv.w;
        *(float4*)(og + base + (size_t)tid * 128 + d4 * 4) = r;
    }
}

// ---------------------------------------------------------------------------
extern "C" void kernel_launch(void* const* d_in, const int* in_sizes, int n_in,
                              void* d_out, int out_size, void* d_ws, size_t ws_size,
                              hipStream_t stream) {
    const float* x    = (const float*)d_in[0];
    const float* mask = (const float*)d_in[1];
    const float* ln_w = (const float*)d_in[2];
    const float* ln_b = (const float*)d_in[3];
    const float* tri_w= (const float*)d_in[4];
    const float* q_w  = (const float*)d_in[5];
    const float* k_w  = (const float*)d_in[6];
    const float* v_w  = (const float*)d_in[7];
    const float* g_w  = (const float*)d_in[8];
    const float* g_b  = (const float*)d_in[9];
    const float* o_w  = (const float*)d_in[10];
    const float* o_b  = (const float*)d_in[11];

    float* ws  = (float*)d_ws;
    float* xn  = ws;                 // [65536][128]; later reused as og
    float* qb  = ws + 8388608;       // [65536][128]
    float* kb  = ws + 16777216;
    float* vb  = ws + 25165824;
    float* gb  = ws + 33554432;
    float* tri = ws + 41943040;      // [4][65536]
    float* out = (float*)d_out;

    ln_tri_kernel<<<16384, 256, 0, stream>>>(x, ln_w, ln_b, tri_w, xn, tri);

    dim3 gg(1024, 2);
    gemm128_kernel<<<gg, 256, 0, stream>>>(xn, q_w, nullptr, qb, 1, 0.17677669529663687f);
    gemm128_kernel<<<gg, 256, 0, stream>>>(xn, k_w, nullptr, kb, 0, 1.0f);
    gemm128_kernel<<<gg, 256, 0, stream>>>(xn, v_w, nullptr, vb, 0, 1.0f);
    gemm128_kernel<<<gg, 256, 0, stream>>>(xn, g_w, g_b, gb, 2, 1.0f);

    dim3 ga(256, 4);
    attn_kernel<<<ga, 256, 0, stream>>>(qb, kb, vb, gb, mask, tri, xn /* og aliases xn */);

    gemm128_kernel<<<gg, 256, 0, stream>>>(xn, o_w, o_b, out, 3, 1.0f);
}

// Round 2
// 219.716 us; speedup vs baseline: 2.1041x; 2.1041x over previous
//
#include <hip/hip_runtime.h>
#include <math.h>

#define NROW 65536      // I*J = 256*256
#define LOG2E_ 1.4426950408889634f

typedef short short8 __attribute__((ext_vector_type(8)));   // 8 x bf16 (4 VGPRs)
typedef float f32x4 __attribute__((ext_vector_type(4)));

#if defined(__has_builtin)
#if __has_builtin(__builtin_amdgcn_exp2f)
#define EXP2F(x) __builtin_amdgcn_exp2f(x)
#else
#define EXP2F(x) exp2f(x)
#endif
#else
#define EXP2F(x) exp2f(x)
#endif

static __device__ __forceinline__ unsigned short f2bf(float f) {
    union { float f; unsigned int u; } c; c.f = f;
    c.u += 0x7fffu + ((c.u >> 16) & 1u);      // RNE (no NaN inputs here)
    return (unsigned short)(c.u >> 16);
}
static __device__ __forceinline__ float bf2f(unsigned short s) {
    union { unsigned int u; float f; } c; c.u = ((unsigned int)s) << 16;
    return c.f;
}

// ---------------------------------------------------------------------------
// Prep: W[128k][128n] fp32 -> Wt[n][k] bf16 (transposed), q_w scaled by
// D^-0.5 * log2(e) so attention can use exp2 directly.
// ---------------------------------------------------------------------------
__global__ __launch_bounds__(256) void prep_w_kernel(
    const float* __restrict__ qw, const float* __restrict__ kw,
    const float* __restrict__ vw, const float* __restrict__ gw,
    const float* __restrict__ ow, unsigned short* __restrict__ wt)
{
    int id = blockIdx.x * 256 + threadIdx.x;      // 0 .. 81919
    int wsel = id >> 14;
    int e = id & 16383;
    int kk = e >> 7, n = e & 127;
    const float* src = (wsel == 0) ? qw : (wsel == 1) ? kw : (wsel == 2) ? vw
                     : (wsel == 3) ? gw : ow;
    float scale = (wsel == 0) ? (0.17677669529663687f * LOG2E_) : 1.0f;
    wt[wsel * 16384 + n * 128 + kk] = f2bf(src[kk * 128 + n] * scale);
}

// ---------------------------------------------------------------------------
// LayerNorm -> xn (bf16) + tri bias (fp32, pre-scaled by log2e), [h][i*256+j]
// One wave per row, 4 rows / 256-thread block.
// ---------------------------------------------------------------------------
__global__ __launch_bounds__(256) void ln_tri_kernel(
    const float* __restrict__ x, const float* __restrict__ ln_w,
    const float* __restrict__ ln_b, const float* __restrict__ tri_w,
    unsigned short* __restrict__ xn, float* __restrict__ tri)
{
    int row  = (blockIdx.x * 256 + threadIdx.x) >> 6;
    int lane = threadIdx.x & 63;

    float2 xv = *(const float2*)(x + (size_t)row * 128 + lane * 2);

    float s = xv.x + xv.y;
    #pragma unroll
    for (int m = 32; m >= 1; m >>= 1) s += __shfl_xor(s, m, 64);
    float mu = s * (1.0f / 128.0f);

    float d0 = xv.x - mu, d1 = xv.y - mu;
    float sq = d0 * d0 + d1 * d1;
    #pragma unroll
    for (int m = 32; m >= 1; m >>= 1) sq += __shfl_xor(sq, m, 64);
    float rstd = rsqrtf(sq * (1.0f / 128.0f) + 1e-5f);

    float2 wv = *(const float2*)(ln_w + lane * 2);
    float2 bv = *(const float2*)(ln_b + lane * 2);
    float n0 = d0 * rstd * wv.x + bv.x;
    float n1 = d1 * rstd * wv.y + bv.y;

    ushort2 xo; xo.x = f2bf(n0); xo.y = f2bf(n1);
    *(ushort2*)(xn + (size_t)row * 128 + lane * 2) = xo;

    float4 t0 = *(const float4*)(tri_w + (lane * 2) * 4);
    float4 t1 = *(const float4*)(tri_w + (lane * 2 + 1) * 4);
    float ax = n0 * t0.x + n1 * t1.x;
    float ay = n0 * t0.y + n1 * t1.y;
    float az = n0 * t0.z + n1 * t1.z;
    float aw = n0 * t0.w + n1 * t1.w;
    #pragma unroll
    for (int m = 32; m >= 1; m >>= 1) {
        ax += __shfl_xor(ax, m, 64);
        ay += __shfl_xor(ay, m, 64);
        az += __shfl_xor(az, m, 64);
        aw += __shfl_xor(aw, m, 64);
    }
    if (lane < 4) {
        float v = (lane == 0) ? ax : (lane == 1) ? ay : (lane == 2) ? az : aw;
        tri[(size_t)lane * NROW + row] = v * LOG2E_;
    }
}

// ---------------------------------------------------------------------------
// bf16 MFMA GEMM: C[M,128] = A[M,128] @ W[128,128], Wt is [n][k] bf16.
// 128x128 tile / 256-thread block (4 waves, each 64x64).
// mode 0: bf16 out, no epilogue; 1: bf16 out sigmoid(x+bias); 2: f32 out x+bias
// ---------------------------------------------------------------------------
__global__ __launch_bounds__(256) void gemm_mfma_kernel(
    const unsigned short* __restrict__ A, const unsigned short* __restrict__ Wt,
    const float* __restrict__ bias, void* __restrict__ out, int mode)
{
    __shared__ __align__(16) unsigned short A_lds[128 * 128];
    __shared__ __align__(16) unsigned short W_lds[128 * 128];

    const int tid = threadIdx.x;
    const int m0 = blockIdx.x * 128;
    const int w = tid >> 6, lane = tid & 63, g = lane >> 4, m = lane & 15;
    const int wr = w >> 1, wc = w & 1;

    // stage A (bf16 copy) + Wt, XOR-swizzled rows (st_16x32 style)
    #pragma unroll
    for (int it = 0; it < 8; ++it) {
        int idx = it * 256 + tid;
        int row = idx >> 4, c8 = idx & 15;
        short8 av = *(const short8*)(A + (size_t)(m0 + row) * 128 + c8 * 8);
        short8 wv = *(const short8*)(Wt + row * 128 + c8 * 8);
        int off = (row * 256 + c8 * 16) ^ ((row & 7) << 4);
        *(short8*)((char*)A_lds + off) = av;
        *(short8*)((char*)W_lds + off) = wv;
    }
    __syncthreads();

    f32x4 acc[4][4];
    #pragma unroll
    for (int mt = 0; mt < 4; ++mt)
        #pragma unroll
        for (int nt = 0; nt < 4; ++nt)
            acc[mt][nt] = (f32x4){0.f, 0.f, 0.f, 0.f};

    #pragma unroll
    for (int kc = 0; kc < 4; ++kc) {
        short8 a[4], b[4];
        #pragma unroll
        for (int mt = 0; mt < 4; ++mt) {
            int row = wr * 64 + mt * 16 + m;
            a[mt] = *(const short8*)((const char*)A_lds +
                     ((row * 256 + kc * 64 + 16 * g) ^ ((row & 7) << 4)));
        }
        #pragma unroll
        for (int nt = 0; nt < 4; ++nt) {
            int row = wc * 64 + nt * 16 + m;
            b[nt] = *(const short8*)((const char*)W_lds +
                     ((row * 256 + kc * 64 + 16 * g) ^ ((row & 7) << 4)));
        }
        #pragma unroll
        for (int mt = 0; mt < 4; ++mt)
            #pragma unroll
            for (int nt = 0; nt < 4; ++nt)
                acc[mt][nt] = __builtin_amdgcn_mfma_f32_16x16x32_bf16(
                                  a[mt], b[nt], acc[mt][nt], 0, 0, 0);
    }

    #pragma unroll
    for (int nt = 0; nt < 4; ++nt) {
        int col = wc * 64 + nt * 16 + m;
        float bn = (mode != 0) ? bias[col] : 0.f;
        #pragma unroll
        for (int mt = 0; mt < 4; ++mt) {
            #pragma unroll
            for (int r = 0; r < 4; ++r) {
                size_t o = (size_t)(m0 + wr * 64 + mt * 16 + 4 * g + r) * 128 + col;
                float val = acc[mt][nt][r];
                if (mode == 0) {
                    ((unsigned short*)out)[o] = f2bf(val);
                } else if (mode == 1) {
                    ((unsigned short*)out)[o] = f2bf(1.0f / (1.0f + __expf(-(val + bn))));
                } else {
                    ((float*)out)[o] = val + bn;
                }
            }
        }
    }
}

// ---------------------------------------------------------------------------
// MFMA attention, block per (i,h), 4 waves x 64 q-rows each.
// Swapped QK^T (mfma(K,Q) -> S^T), exact single-pass softmax (full key row in
// regs), P via per-wave LDS, PV with column-major padded V. exp2 throughout
// (log2e pre-folded into q_w / tri / mask bias).
// ---------------------------------------------------------------------------
__global__ __launch_bounds__(256) void attn_mfma_kernel(
    const unsigned short* __restrict__ q, const unsigned short* __restrict__ k,
    const unsigned short* __restrict__ v, const unsigned short* __restrict__ gb,
    const float* __restrict__ mask, const float* __restrict__ tri,
    unsigned short* __restrict__ og)
{
    __shared__ __align__(16) unsigned short K_lds[256 * 40];   // row-major, pad 40
    __shared__ __align__(16) unsigned short Vc[32 * 264];      // col-major, pad 264
    __shared__ __align__(16) unsigned short P_lds[4 * 16 * 264];
    __shared__ float mb[256];

    const int i = blockIdx.x, h = blockIdx.y;
    const int tid = threadIdx.x;
    const int w = tid >> 6, lane = tid & 63, g = lane >> 4, m = lane & 15;

    const size_t base = (size_t)i * 256 * 128 + h * 32;   // elem offset [65536][128]

    // stage K (row-major) and V (transposed)
    #pragma unroll
    for (int it = 0; it < 4; ++it) {
        int idx = it * 256 + tid;
        int j = idx >> 2, d0 = (idx & 3) * 8;
        short8 kv = *(const short8*)(k + base + (size_t)j * 128 + d0);
        short8 vv = *(const short8*)(v + base + (size_t)j * 128 + d0);
        *(short8*)((char*)K_lds + j * 80 + d0 * 2) = kv;
        unsigned short* vp = (unsigned short*)&vv;
        #pragma unroll
        for (int e = 0; e < 8; ++e) Vc[(d0 + e) * 264 + j] = vp[e];
    }
    mb[tid] = (mask[i * 256 + tid] - 1.0f) * (1.0e9f * LOG2E_);

    // Q fragments: lane holds Q[q=qt*16+m][8g..8g+7] for this wave's 4 q-tiles
    short8 qf[4];
    #pragma unroll
    for (int t = 0; t < 4; ++t)
        qf[t] = *(const short8*)(q + base + (size_t)(w * 64 + t * 16 + m) * 128 + 8 * g);

    __syncthreads();

    char* Pw = (char*)P_lds + w * 8448;
    const f32x4 zero = {0.f, 0.f, 0.f, 0.f};

    #pragma unroll 1
    for (int t = 0; t < 4; ++t) {
        const int qloc = w * 64 + t * 16 + m;     // this lane's q (for S^T cols)

        // QK^T: acc[kt] holds S^T[key = kt*16+4g+r][q = qloc]
        f32x4 acc[16];
        #pragma unroll
        for (int kt = 0; kt < 16; ++kt) {
            short8 af = *(const short8*)((const char*)K_lds + (kt * 16 + m) * 80 + 16 * g);
            acc[kt] = __builtin_amdgcn_mfma_f32_16x16x32_bf16(af, qf[t], zero, 0, 0, 0);
        }

        // biases (already log2e-scaled)
        #pragma unroll
        for (int kt = 0; kt < 16; ++kt) {
            f32x4 mbv = *(const f32x4*)(&mb[kt * 16 + 4 * g]);
            f32x4 tv  = *(const f32x4*)(tri + (size_t)h * NROW +
                                        (size_t)qloc * 256 + kt * 16 + 4 * g);
            acc[kt] += mbv + tv;
        }

        // exact softmax: full 256-key row lives in 4 lane-groups x 16 regs
        float mx = -3.0e38f;
        #pragma unroll
        for (int kt = 0; kt < 16; ++kt)
            mx = fmaxf(mx, fmaxf(fmaxf(acc[kt][0], acc[kt][1]),
                                 fmaxf(acc[kt][2], acc[kt][3])));
        mx = fmaxf(mx, __shfl_xor(mx, 16));
        mx = fmaxf(mx, __shfl_xor(mx, 32));

        float ls = 0.f;
        #pragma unroll
        for (int kt = 0; kt < 16; ++kt) {
            float p0 = EXP2F(acc[kt][0] - mx);
            float p1 = EXP2F(acc[kt][1] - mx);
            float p2 = EXP2F(acc[kt][2] - mx);
            float p3 = EXP2F(acc[kt][3] - mx);
            ls += (p0 + p1) + (p2 + p3);
            ushort4 pk;
            pk.x = f2bf(p0); pk.y = f2bf(p1); pk.z = f2bf(p2); pk.w = f2bf(p3);
            *(ushort4*)(Pw + m * 528 + kt * 32 + 8 * g) = pk;   // P[q=m][key]
        }
        ls += __shfl_xor(ls, 16);
        ls += __shfl_xor(ls, 32);

        // PV: O[q][d] = P[16x256] @ V[256x32]
        f32x4 o0 = zero, o1 = zero;
        #pragma unroll
        for (int kc = 0; kc < 8; ++kc) {
            short8 pa = *(const short8*)(Pw + m * 528 + kc * 64 + 16 * g);
            short8 v0 = *(const short8*)((const char*)Vc + m * 528 + kc * 64 + 16 * g);
            short8 v1 = *(const short8*)((const char*)Vc + (16 + m) * 528 + kc * 64 + 16 * g);
            o0 = __builtin_amdgcn_mfma_f32_16x16x32_bf16(pa, v0, o0, 0, 0, 0);
            o1 = __builtin_amdgcn_mfma_f32_16x16x32_bf16(pa, v1, o1, 0, 0, 0);
        }

        // epilogue: divide by row-sum, gate, store bf16
        float inv[4];
        #pragma unroll
        for (int r = 0; r < 4; ++r) inv[r] = 1.0f / __shfl(ls, 4 * g + r);

        #pragma unroll
        for (int r = 0; r < 4; ++r) {
            size_t rowoff = base + (size_t)(w * 64 + t * 16 + 4 * g + r) * 128;
            float gv0 = bf2f(gb[rowoff + m]);
            float gv1 = bf2f(gb[rowoff + 16 + m]);
            og[rowoff + m]      = f2bf(o0[r] * inv[r] * gv0);
            og[rowoff + 16 + m] = f2bf(o1[r] * inv[r] * gv1);
        }
    }
}

// ---------------------------------------------------------------------------
extern "C" void kernel_launch(void* const* d_in, const int* in_sizes, int n_in,
                              void* d_out, int out_size, void* d_ws, size_t ws_size,
                              hipStream_t stream) {
    (void)in_sizes; (void)n_in; (void)out_size; (void)ws_size;
    const float* x    = (const float*)d_in[0];
    const float* mask = (const float*)d_in[1];
    const float* ln_w = (const float*)d_in[2];
    const float* ln_b = (const float*)d_in[3];
    const float* tri_w= (const float*)d_in[4];
    const float* q_w  = (const float*)d_in[5];
    const float* k_w  = (const float*)d_in[6];
    const float* v_w  = (const float*)d_in[7];
    const float* g_w  = (const float*)d_in[8];
    const float* g_b  = (const float*)d_in[9];
    const float* o_w  = (const float*)d_in[10];
    const float* o_b  = (const float*)d_in[11];

    char* ws = (char*)d_ws;
    unsigned short* xn  = (unsigned short*)(ws);                 // 16 MB bf16
    unsigned short* qb  = (unsigned short*)(ws + 16777216);      // 16 MB
    unsigned short* kb  = (unsigned short*)(ws + 33554432);      // 16 MB
    unsigned short* vb  = (unsigned short*)(ws + 50331648);      // 16 MB
    unsigned short* gbf = (unsigned short*)(ws + 67108864);      // 16 MB
    unsigned short* ogb = (unsigned short*)(ws + 83886080);      // 16 MB
    float*          tri = (float*)(ws + 100663296);              // 1 MB
    unsigned short* wt  = (unsigned short*)(ws + 101711872);     // 160 KB

    prep_w_kernel<<<320, 256, 0, stream>>>(q_w, k_w, v_w, g_w, o_w, wt);
    ln_tri_kernel<<<16384, 256, 0, stream>>>(x, ln_w, ln_b, tri_w, xn, tri);

    gemm_mfma_kernel<<<512, 256, 0, stream>>>(xn, wt,          nullptr, qb, 0);
    gemm_mfma_kernel<<<512, 256, 0, stream>>>(xn, wt + 16384,  nullptr, kb, 0);
    gemm_mfma_kernel<<<512, 256, 0, stream>>>(xn, wt + 32768,  nullptr, vb, 0);
    gemm_mfma_kernel<<<512, 256, 0, stream>>>(xn, wt + 49152,  g_b,     gbf, 1);

    dim3 ga(256, 4);
    attn_mfma_kernel<<<ga, 256, 0, stream>>>(qb, kb, vb, gbf, mask, tri, ogb);

    gemm_mfma_kernel<<<512, 256, 0, stream>>>(ogb, wt + 65536, o_b, (float*)d_out, 2);
}

// Round 3
// 191.662 us; speedup vs baseline: 2.4121x; 1.1464x over previous
//
#include <hip/hip_runtime.h>
#include <hip/hip_bf16.h>
#include <math.h>

#define NROW 65536      // I*J = 256*256
#define LOG2E_ 1.4426950408889634f

typedef short short8 __attribute__((ext_vector_type(8)));   // 8 x bf16 (4 VGPRs)
typedef float f32x4 __attribute__((ext_vector_type(4)));

#if defined(__has_builtin)
#if __has_builtin(__builtin_amdgcn_exp2f)
#define EXP2F(x) __builtin_amdgcn_exp2f(x)
#else
#define EXP2F(x) exp2f(x)
#endif
#else
#define EXP2F(x) exp2f(x)
#endif

static __device__ __forceinline__ unsigned short f2bf(float f) {
    union { float f; unsigned int u; } c; c.f = f;
    c.u += 0x7fffu + ((c.u >> 16) & 1u);      // RNE (no NaN inputs here)
    return (unsigned short)(c.u >> 16);
}
static __device__ __forceinline__ float bf2f(unsigned short s) {
    union { unsigned int u; float f; } c; c.u = ((unsigned int)s) << 16;
    return c.f;
}
static __device__ __forceinline__ int pk2bf(float a, float b) {
    union { __hip_bfloat162 h; int i; } u;
    u.h = __float22bfloat162_rn(make_float2(a, b));   // x -> low 16 bits
    return u.i;
}

// ---------------------------------------------------------------------------
// Prep: W[128k][128n] fp32 -> Wt[n][k] bf16 (transposed); q_w pre-scaled by
// D^-0.5 * log2(e) so attention uses exp2 directly.
// ---------------------------------------------------------------------------
__global__ __launch_bounds__(256) void prep_w_kernel(
    const float* __restrict__ qw, const float* __restrict__ kw,
    const float* __restrict__ vw, const float* __restrict__ gw,
    const float* __restrict__ ow, unsigned short* __restrict__ wt)
{
    int id = blockIdx.x * 256 + threadIdx.x;      // 0 .. 81919
    int wsel = id >> 14;
    int e = id & 16383;
    int kk = e >> 7, n = e & 127;
    const float* src = (wsel == 0) ? qw : (wsel == 1) ? kw : (wsel == 2) ? vw
                     : (wsel == 3) ? gw : ow;
    float scale = (wsel == 0) ? (0.17677669529663687f * LOG2E_) : 1.0f;
    wt[wsel * 16384 + n * 128 + kk] = f2bf(src[kk * 128 + n] * scale);
}

// ---------------------------------------------------------------------------
// LayerNorm -> xn (bf16) + tri bias (bf16, pre-scaled by log2e), [h][q][k]
// ---------------------------------------------------------------------------
__global__ __launch_bounds__(256) void ln_tri_kernel(
    const float* __restrict__ x, const float* __restrict__ ln_w,
    const float* __restrict__ ln_b, const float* __restrict__ tri_w,
    unsigned short* __restrict__ xn, unsigned short* __restrict__ tri)
{
    int row  = (blockIdx.x * 256 + threadIdx.x) >> 6;
    int lane = threadIdx.x & 63;

    float2 xv = *(const float2*)(x + (size_t)row * 128 + lane * 2);

    float s = xv.x + xv.y;
    #pragma unroll
    for (int m = 32; m >= 1; m >>= 1) s += __shfl_xor(s, m, 64);
    float mu = s * (1.0f / 128.0f);

    float d0 = xv.x - mu, d1 = xv.y - mu;
    float sq = d0 * d0 + d1 * d1;
    #pragma unroll
    for (int m = 32; m >= 1; m >>= 1) sq += __shfl_xor(sq, m, 64);
    float rstd = rsqrtf(sq * (1.0f / 128.0f) + 1e-5f);

    float2 wv = *(const float2*)(ln_w + lane * 2);
    float2 bv = *(const float2*)(ln_b + lane * 2);
    float n0 = d0 * rstd * wv.x + bv.x;
    float n1 = d1 * rstd * wv.y + bv.y;

    ushort2 xo; xo.x = f2bf(n0); xo.y = f2bf(n1);
    *(ushort2*)(xn + (size_t)row * 128 + lane * 2) = xo;

    float4 t0 = *(const float4*)(tri_w + (lane * 2) * 4);
    float4 t1 = *(const float4*)(tri_w + (lane * 2 + 1) * 4);
    float ax = n0 * t0.x + n1 * t1.x;
    float ay = n0 * t0.y + n1 * t1.y;
    float az = n0 * t0.z + n1 * t1.z;
    float aw = n0 * t0.w + n1 * t1.w;
    #pragma unroll
    for (int m = 32; m >= 1; m >>= 1) {
        ax += __shfl_xor(ax, m, 64);
        ay += __shfl_xor(ay, m, 64);
        az += __shfl_xor(az, m, 64);
        aw += __shfl_xor(aw, m, 64);
    }
    if (lane < 4) {
        float v = (lane == 0) ? ax : (lane == 1) ? ay : (lane == 2) ? az : aw;
        tri[(size_t)lane * NROW + row] = f2bf(v * LOG2E_);
    }
}

// ---------------------------------------------------------------------------
// Fused projections: xn @ {q,k,v,g}_w. A staged once; W streamed per target.
// Swapped mfma(b,a) -> C^T layout: lane holds 4 consecutive out-cols ->
// ushort4 stores. wsel==3 gets sigmoid(x + g_b).
// ---------------------------------------------------------------------------
__global__ __launch_bounds__(256) void proj4_kernel(
    const unsigned short* __restrict__ A, const unsigned short* __restrict__ wt,
    const float* __restrict__ g_b,
    unsigned short* __restrict__ qb, unsigned short* __restrict__ kb,
    unsigned short* __restrict__ vb, unsigned short* __restrict__ gb)
{
    __shared__ __align__(16) unsigned short A_lds[128 * 128];
    __shared__ __align__(16) unsigned short W_lds[128 * 128];

    const int tid = threadIdx.x;
    const int m0 = blockIdx.x * 128;
    const int w = tid >> 6, lane = tid & 63, g = lane >> 4, m = lane & 15;
    const int wr = w >> 1, wc = w & 1;

    #pragma unroll
    for (int it = 0; it < 8; ++it) {
        int idx = it * 256 + tid;
        int row = idx >> 4, c8 = idx & 15;
        short8 av = *(const short8*)(A + (size_t)(m0 + row) * 128 + c8 * 8);
        int off = (row * 256 + c8 * 16) ^ ((row & 7) << 4);
        *(short8*)((char*)A_lds + off) = av;
    }

    unsigned short* outp[4] = {qb, kb, vb, gb};
    for (int wsel = 0; wsel < 4; ++wsel) {
        __syncthreads();   // also covers A-stage on first iteration
        #pragma unroll
        for (int it = 0; it < 8; ++it) {
            int idx = it * 256 + tid;
            int row = idx >> 4, c8 = idx & 15;
            short8 wv = *(const short8*)(wt + wsel * 16384 + row * 128 + c8 * 8);
            int off = (row * 256 + c8 * 16) ^ ((row & 7) << 4);
            *(short8*)((char*)W_lds + off) = wv;
        }
        __syncthreads();

        f32x4 acc[4][4];
        #pragma unroll
        for (int mt = 0; mt < 4; ++mt)
            #pragma unroll
            for (int nt = 0; nt < 4; ++nt) acc[mt][nt] = (f32x4){0.f,0.f,0.f,0.f};

        #pragma unroll
        for (int kc = 0; kc < 4; ++kc) {
            short8 a[4], b[4];
            #pragma unroll
            for (int mt = 0; mt < 4; ++mt) {
                int row = wr * 64 + mt * 16 + m;
                a[mt] = *(const short8*)((const char*)A_lds +
                         ((row * 256 + kc * 64 + 16 * g) ^ ((row & 7) << 4)));
            }
            #pragma unroll
            for (int nt = 0; nt < 4; ++nt) {
                int row = wc * 64 + nt * 16 + m;
                b[nt] = *(const short8*)((const char*)W_lds +
                         ((row * 256 + kc * 64 + 16 * g) ^ ((row & 7) << 4)));
            }
            #pragma unroll
            for (int mt = 0; mt < 4; ++mt)
                #pragma unroll
                for (int nt = 0; nt < 4; ++nt)
                    acc[mt][nt] = __builtin_amdgcn_mfma_f32_16x16x32_bf16(
                                      b[nt], a[mt], acc[mt][nt], 0, 0, 0);
        }

        unsigned short* OB = outp[wsel];
        #pragma unroll
        for (int nt = 0; nt < 4; ++nt) {
            int col = wc * 64 + nt * 16 + 4 * g;
            float4 bv = make_float4(0.f,0.f,0.f,0.f);
            if (wsel == 3) bv = *(const float4*)(g_b + col);
            #pragma unroll
            for (int mt = 0; mt < 4; ++mt) {
                int row = m0 + wr * 64 + mt * 16 + m;
                float v0 = acc[mt][nt][0], v1 = acc[mt][nt][1];
                float v2 = acc[mt][nt][2], v3 = acc[mt][nt][3];
                if (wsel == 3) {
                    v0 = 1.0f / (1.0f + __expf(-(v0 + bv.x)));
                    v1 = 1.0f / (1.0f + __expf(-(v1 + bv.y)));
                    v2 = 1.0f / (1.0f + __expf(-(v2 + bv.z)));
                    v3 = 1.0f / (1.0f + __expf(-(v3 + bv.w)));
                }
                ushort4 o;
                o.x = f2bf(v0); o.y = f2bf(v1); o.z = f2bf(v2); o.w = f2bf(v3);
                *(ushort4*)(OB + (size_t)row * 128 + col) = o;
            }
        }
    }
}

// ---------------------------------------------------------------------------
// Output projection: out[M,128] = og @ o_w + o_b (f32 out, float4 stores).
// ---------------------------------------------------------------------------
__global__ __launch_bounds__(256) void oproj_kernel(
    const unsigned short* __restrict__ A, const unsigned short* __restrict__ Wt,
    const float* __restrict__ bias, float* __restrict__ out)
{
    __shared__ __align__(16) unsigned short A_lds[128 * 128];
    __shared__ __align__(16) unsigned short W_lds[128 * 128];

    const int tid = threadIdx.x;
    const int m0 = blockIdx.x * 128;
    const int w = tid >> 6, lane = tid & 63, g = lane >> 4, m = lane & 15;
    const int wr = w >> 1, wc = w & 1;

    #pragma unroll
    for (int it = 0; it < 8; ++it) {
        int idx = it * 256 + tid;
        int row = idx >> 4, c8 = idx & 15;
        short8 av = *(const short8*)(A + (size_t)(m0 + row) * 128 + c8 * 8);
        short8 wv = *(const short8*)(Wt + row * 128 + c8 * 8);
        int off = (row * 256 + c8 * 16) ^ ((row & 7) << 4);
        *(short8*)((char*)A_lds + off) = av;
        *(short8*)((char*)W_lds + off) = wv;
    }
    __syncthreads();

    f32x4 acc[4][4];
    #pragma unroll
    for (int mt = 0; mt < 4; ++mt)
        #pragma unroll
        for (int nt = 0; nt < 4; ++nt) acc[mt][nt] = (f32x4){0.f,0.f,0.f,0.f};

    #pragma unroll
    for (int kc = 0; kc < 4; ++kc) {
        short8 a[4], b[4];
        #pragma unroll
        for (int mt = 0; mt < 4; ++mt) {
            int row = wr * 64 + mt * 16 + m;
            a[mt] = *(const short8*)((const char*)A_lds +
                     ((row * 256 + kc * 64 + 16 * g) ^ ((row & 7) << 4)));
        }
        #pragma unroll
        for (int nt = 0; nt < 4; ++nt) {
            int row = wc * 64 + nt * 16 + m;
            b[nt] = *(const short8*)((const char*)W_lds +
                     ((row * 256 + kc * 64 + 16 * g) ^ ((row & 7) << 4)));
        }
        #pragma unroll
        for (int mt = 0; mt < 4; ++mt)
            #pragma unroll
            for (int nt = 0; nt < 4; ++nt)
                acc[mt][nt] = __builtin_amdgcn_mfma_f32_16x16x32_bf16(
                                  b[nt], a[mt], acc[mt][nt], 0, 0, 0);
    }

    #pragma unroll
    for (int nt = 0; nt < 4; ++nt) {
        int col = wc * 64 + nt * 16 + 4 * g;
        float4 bv = *(const float4*)(bias + col);
        #pragma unroll
        for (int mt = 0; mt < 4; ++mt) {
            int row = m0 + wr * 64 + mt * 16 + m;
            float4 o;
            o.x = acc[mt][nt][0] + bv.x;
            o.y = acc[mt][nt][1] + bv.y;
            o.z = acc[mt][nt][2] + bv.z;
            o.w = acc[mt][nt][3] + bv.w;
            *(float4*)(out + (size_t)row * 128 + col) = o;
        }
    }
}

// ---------------------------------------------------------------------------
// MFMA attention, block per (i,h), 4 waves x 4 q-tiles. No max-subtraction
// (scores bounded), no P LDS: 4-lane-group exchange via ds_bpermute with a
// parity-relabeled slot layout (odd g-groups store kt^1).
// ---------------------------------------------------------------------------
__global__ __launch_bounds__(256, 3) void attn_kernel(
    const unsigned short* __restrict__ q, const unsigned short* __restrict__ k,
    const unsigned short* __restrict__ v, const unsigned short* __restrict__ gate,
    const float* __restrict__ mask, const unsigned short* __restrict__ tri,
    unsigned short* __restrict__ og)
{
    __shared__ __align__(16) unsigned short K_lds[256 * 40];   // 80B rows
    __shared__ __align__(16) unsigned short Vc[32 * 264];      // col-major, pad
    __shared__ float mb[256];

    const int i = blockIdx.x, h = blockIdx.y;
    const int tid = threadIdx.x;
    const int w = tid >> 6, lane = tid & 63, g = lane >> 4, m = lane & 15;
    const size_t base = (size_t)i * 32768 + h * 32;

    #pragma unroll
    for (int it = 0; it < 4; ++it) {
        int idx = it * 256 + tid;
        int j = idx >> 2, d0 = (idx & 3) * 8;
        short8 kv = *(const short8*)(k + base + (size_t)j * 128 + d0);
        short8 vv = *(const short8*)(v + base + (size_t)j * 128 + d0);
        *(short8*)((char*)K_lds + j * 80 + d0 * 2) = kv;
        unsigned short* vp = (unsigned short*)&vv;
        #pragma unroll
        for (int e = 0; e < 8; ++e) Vc[(d0 + e) * 264 + j] = vp[e];
    }
    mb[tid] = (mask[i * 256 + tid] - 1.0f) * (1.0e9f * LOG2E_);
    __syncthreads();

    // bpermute lane indices: classA srcs [0,2,1,3], classB = srcA^1
    const int srcA = ((g & 1) << 1) | (g >> 1);
    const int idxA = (srcA * 16 + m) * 4;
    const int idxB = idxA ^ 64;
    const bool low = (lane < 32);
    const bool odd = (g & 1);
    const char* VcB0 = (const char*)Vc + m * 528;
    const char* VcB1 = (const char*)Vc + (16 + m) * 528;
    const f32x4 zero = {0.f, 0.f, 0.f, 0.f};

    #pragma unroll 1
    for (int t = 0; t < 4; ++t) {
        const int qrow = w * 64 + t * 16 + m;
        const short8 qf = *(const short8*)(q + base + (size_t)qrow * 128 + 8 * g);
        const unsigned short* triP = tri + (size_t)h * NROW + (size_t)qrow * 256;

        int pk[32];
        float ls = 0.f;

        #pragma unroll
        for (int ktp = 0; ktp < 8; ++ktp) {
            int d00, d01, d10, d11;
            {
                const int kt = 2 * ktp;
                short8 af = *(const short8*)((const char*)K_lds + (kt * 16 + m) * 80 + 16 * g);
                f32x4 acc = __builtin_amdgcn_mfma_f32_16x16x32_bf16(af, qf, zero, 0, 0, 0);
                f32x4 mbv = *(const f32x4*)(mb + kt * 16 + 4 * g);
                int2 td = *(const int2*)(triP + kt * 16 + 4 * g);
                float t0 = __uint_as_float((unsigned)td.x << 16);
                float t1 = __uint_as_float((unsigned)td.x & 0xffff0000u);
                float t2 = __uint_as_float((unsigned)td.y << 16);
                float t3 = __uint_as_float((unsigned)td.y & 0xffff0000u);
                float p0 = EXP2F(acc[0] + mbv[0] + t0);
                float p1 = EXP2F(acc[1] + mbv[1] + t1);
                float p2 = EXP2F(acc[2] + mbv[2] + t2);
                float p3 = EXP2F(acc[3] + mbv[3] + t3);
                ls += (p0 + p1) + (p2 + p3);
                d00 = pk2bf(p0, p1); d01 = pk2bf(p2, p3);
            }
            {
                const int kt = 2 * ktp + 1;
                short8 af = *(const short8*)((const char*)K_lds + (kt * 16 + m) * 80 + 16 * g);
                f32x4 acc = __builtin_amdgcn_mfma_f32_16x16x32_bf16(af, qf, zero, 0, 0, 0);
                f32x4 mbv = *(const f32x4*)(mb + kt * 16 + 4 * g);
                int2 td = *(const int2*)(triP + kt * 16 + 4 * g);
                float t0 = __uint_as_float((unsigned)td.x << 16);
                float t1 = __uint_as_float((unsigned)td.x & 0xffff0000u);
                float t2 = __uint_as_float((unsigned)td.y << 16);
                float t3 = __uint_as_float((unsigned)td.y & 0xffff0000u);
                float p0 = EXP2F(acc[0] + mbv[0] + t0);
                float p1 = EXP2F(acc[1] + mbv[1] + t1);
                float p2 = EXP2F(acc[2] + mbv[2] + t2);
                float p3 = EXP2F(acc[3] + mbv[3] + t3);
                ls += (p0 + p1) + (p2 + p3);
                d10 = pk2bf(p0, p1); d11 = pk2bf(p2, p3);
            }
            // parity relabel: odd g-groups store kt^1 in the kt slot-pair
            pk[4 * ktp + 0] = odd ? d10 : d00;
            pk[4 * ktp + 1] = odd ? d11 : d01;
            pk[4 * ktp + 2] = odd ? d00 : d10;
            pk[4 * ktp + 3] = odd ? d01 : d11;
        }
        ls += __shfl_xor(ls, 16, 64);
        ls += __shfl_xor(ls, 32, 64);

        f32x4 o0 = zero, o1 = zero;
        #pragma unroll
        for (int c = 0; c < 8; ++c) {
            int dA0 = __builtin_amdgcn_ds_bpermute(idxA, pk[4 * c + 0]);
            int dA1 = __builtin_amdgcn_ds_bpermute(idxA, pk[4 * c + 1]);
            int dB0 = __builtin_amdgcn_ds_bpermute(idxB, pk[4 * c + 2]);
            int dB1 = __builtin_amdgcn_ds_bpermute(idxB, pk[4 * c + 3]);
            union { int4 i4; short8 s8; } bu;
            bu.i4.x = low ? dA0 : dB0;
            bu.i4.y = low ? dA1 : dB1;
            bu.i4.z = low ? dB0 : dA0;
            bu.i4.w = low ? dB1 : dA1;
            short8 av0 = *(const short8*)(VcB0 + c * 64 + 16 * g);
            short8 av1 = *(const short8*)(VcB1 + c * 64 + 16 * g);
            o0 = __builtin_amdgcn_mfma_f32_16x16x32_bf16(av0, bu.s8, o0, 0, 0, 0);
            o1 = __builtin_amdgcn_mfma_f32_16x16x32_bf16(av1, bu.s8, o1, 0, 0, 0);
        }

        float inv = 1.0f / ls;
        size_t ro = base + (size_t)qrow * 128;
        ushort4 g0 = *(const ushort4*)(gate + ro + 4 * g);
        ushort4 g1 = *(const ushort4*)(gate + ro + 16 + 4 * g);
        ushort4 s0, s1;
        s0.x = f2bf(o0[0] * inv * bf2f(g0.x));
        s0.y = f2bf(o0[1] * inv * bf2f(g0.y));
        s0.z = f2bf(o0[2] * inv * bf2f(g0.z));
        s0.w = f2bf(o0[3] * inv * bf2f(g0.w));
        s1.x = f2bf(o1[0] * inv * bf2f(g1.x));
        s1.y = f2bf(o1[1] * inv * bf2f(g1.y));
        s1.z = f2bf(o1[2] * inv * bf2f(g1.z));
        s1.w = f2bf(o1[3] * inv * bf2f(g1.w));
        *(ushort4*)(og + ro + 4 * g) = s0;
        *(ushort4*)(og + ro + 16 + 4 * g) = s1;
    }
}

// ---------------------------------------------------------------------------
extern "C" void kernel_launch(void* const* d_in, const int* in_sizes, int n_in,
                              void* d_out, int out_size, void* d_ws, size_t ws_size,
                              hipStream_t stream) {
    (void)in_sizes; (void)n_in; (void)out_size; (void)ws_size;
    const float* x    = (const float*)d_in[0];
    const float* mask = (const float*)d_in[1];
    const float* ln_w = (const float*)d_in[2];
    const float* ln_b = (const float*)d_in[3];
    const float* tri_w= (const float*)d_in[4];
    const float* q_w  = (const float*)d_in[5];
    const float* k_w  = (const float*)d_in[6];
    const float* v_w  = (const float*)d_in[7];
    const float* g_w  = (const float*)d_in[8];
    const float* g_b  = (const float*)d_in[9];
    const float* o_w  = (const float*)d_in[10];
    const float* o_b  = (const float*)d_in[11];

    char* ws = (char*)d_ws;
    unsigned short* xn  = (unsigned short*)(ws);                 // 16 MB
    unsigned short* qb  = (unsigned short*)(ws + 16777216);
    unsigned short* kb  = (unsigned short*)(ws + 33554432);
    unsigned short* vb  = (unsigned short*)(ws + 50331648);
    unsigned short* gbf = (unsigned short*)(ws + 67108864);
    unsigned short* ogb = (unsigned short*)(ws + 83886080);
    unsigned short* tri = (unsigned short*)(ws + 100663296);     // 512 KB bf16
    unsigned short* wt  = (unsigned short*)(ws + 101711872);     // 160 KB

    prep_w_kernel<<<320, 256, 0, stream>>>(q_w, k_w, v_w, g_w, o_w, wt);
    ln_tri_kernel<<<16384, 256, 0, stream>>>(x, ln_w, ln_b, tri_w, xn, tri);

    proj4_kernel<<<512, 256, 0, stream>>>(xn, wt, g_b, qb, kb, vb, gbf);

    dim3 ga(256, 4);
    attn_kernel<<<ga, 256, 0, stream>>>(qb, kb, vb, gbf, mask, tri, ogb);

    oproj_kernel<<<512, 256, 0, stream>>>(ogb, wt + 65536, o_b, (float*)d_out);
}

// Round 4
// 171.891 us; speedup vs baseline: 2.6895x; 1.1150x over previous
//
#include <hip/hip_runtime.h>
#include <hip/hip_bf16.h>
#include <math.h>

#define NROW 65536      // I*J = 256*256
#define LOG2E_ 1.4426950408889634f
#define HSTRIDE 2097152 // 65536*32 elems per head

typedef short short8 __attribute__((ext_vector_type(8)));   // 8 x bf16 (4 VGPRs)
typedef float f32x4 __attribute__((ext_vector_type(4)));

#if defined(__has_builtin)
#if __has_builtin(__builtin_amdgcn_exp2f)
#define EXP2F(x) __builtin_amdgcn_exp2f(x)
#else
#define EXP2F(x) exp2f(x)
#endif
#else
#define EXP2F(x) exp2f(x)
#endif

static __device__ __forceinline__ unsigned short f2bf(float f) {
    union { float f; unsigned int u; } c; c.f = f;
    c.u += 0x7fffu + ((c.u >> 16) & 1u);      // RNE (no NaN inputs here)
    return (unsigned short)(c.u >> 16);
}
static __device__ __forceinline__ float bf2f(unsigned short s) {
    union { unsigned int u; float f; } c; c.u = ((unsigned int)s) << 16;
    return c.f;
}
static __device__ __forceinline__ int pk2bf(float a, float b) {
    union { __hip_bfloat162 h; int i; } u;
    u.h = __float22bfloat162_rn(make_float2(a, b));   // x -> low 16 bits
    return u.i;
}

// ---------------------------------------------------------------------------
// Prep: W[128k][128n] fp32 -> Wt[n][k] bf16 (transposed); q_w pre-scaled by
// D^-0.5 * log2(e) so attention uses exp2 directly.
// ---------------------------------------------------------------------------
__global__ __launch_bounds__(256) void prep_w_kernel(
    const float* __restrict__ qw, const float* __restrict__ kw,
    const float* __restrict__ vw, const float* __restrict__ gw,
    const float* __restrict__ ow, unsigned short* __restrict__ wt)
{
    int id = blockIdx.x * 256 + threadIdx.x;      // 0 .. 81919
    int wsel = id >> 14;
    int e = id & 16383;
    int kk = e >> 7, n = e & 127;
    const float* src = (wsel == 0) ? qw : (wsel == 1) ? kw : (wsel == 2) ? vw
                     : (wsel == 3) ? gw : ow;
    float scale = (wsel == 0) ? (0.17677669529663687f * LOG2E_) : 1.0f;
    wt[wsel * 16384 + n * 128 + kk] = f2bf(src[kk * 128 + n] * scale);
}

// ---------------------------------------------------------------------------
// LayerNorm -> xn (bf16) + tri bias (bf16, log2e-scaled) in MFMA-tiled layout:
// triT[h][qt][kt][m][kc] : offset = h*65536 + qt*4096 + kt*256 + m*16 + kc
// ---------------------------------------------------------------------------
__global__ __launch_bounds__(256) void ln_tri_kernel(
    const float* __restrict__ x, const float* __restrict__ ln_w,
    const float* __restrict__ ln_b, const float* __restrict__ tri_w,
    unsigned short* __restrict__ xn, unsigned short* __restrict__ triT)
{
    int row  = (blockIdx.x * 256 + threadIdx.x) >> 6;
    int lane = threadIdx.x & 63;

    float2 xv = *(const float2*)(x + (size_t)row * 128 + lane * 2);

    float s = xv.x + xv.y;
    #pragma unroll
    for (int m = 32; m >= 1; m >>= 1) s += __shfl_xor(s, m, 64);
    float mu = s * (1.0f / 128.0f);

    float d0 = xv.x - mu, d1 = xv.y - mu;
    float sq = d0 * d0 + d1 * d1;
    #pragma unroll
    for (int m = 32; m >= 1; m >>= 1) sq += __shfl_xor(sq, m, 64);
    float rstd = rsqrtf(sq * (1.0f / 128.0f) + 1e-5f);

    float2 wv = *(const float2*)(ln_w + lane * 2);
    float2 bv = *(const float2*)(ln_b + lane * 2);
    float n0 = d0 * rstd * wv.x + bv.x;
    float n1 = d1 * rstd * wv.y + bv.y;

    ushort2 xo; xo.x = f2bf(n0); xo.y = f2bf(n1);
    *(ushort2*)(xn + (size_t)row * 128 + lane * 2) = xo;

    float4 t0 = *(const float4*)(tri_w + (lane * 2) * 4);
    float4 t1 = *(const float4*)(tri_w + (lane * 2 + 1) * 4);
    float ax = n0 * t0.x + n1 * t1.x;
    float ay = n0 * t0.y + n1 * t1.y;
    float az = n0 * t0.z + n1 * t1.z;
    float aw = n0 * t0.w + n1 * t1.w;
    #pragma unroll
    for (int m = 32; m >= 1; m >>= 1) {
        ax += __shfl_xor(ax, m, 64);
        ay += __shfl_xor(ay, m, 64);
        az += __shfl_xor(az, m, 64);
        aw += __shfl_xor(aw, m, 64);
    }
    if (lane < 4) {
        float v = (lane == 0) ? ax : (lane == 1) ? ay : (lane == 2) ? az : aw;
        int q = row >> 8, kc = row & 255;
        int off = lane * 65536 + (q >> 4) * 4096 + (kc >> 4) * 256
                + (q & 15) * 16 + (kc & 15);
        triT[off] = f2bf(v * LOG2E_);
    }
}

// ---------------------------------------------------------------------------
// Fused projections: xn @ {q,k,v,g}_w -> head-separated [h][65536][32] bf16.
// Swapped mfma(b,a) -> C^T layout: lane holds 4 consecutive out-cols.
// wsel==3 gets sigmoid(x + g_b).
// ---------------------------------------------------------------------------
__global__ __launch_bounds__(256) void proj4_kernel(
    const unsigned short* __restrict__ A, const unsigned short* __restrict__ wt,
    const float* __restrict__ g_b,
    unsigned short* __restrict__ qh, unsigned short* __restrict__ kh,
    unsigned short* __restrict__ vh, unsigned short* __restrict__ gh)
{
    __shared__ __align__(16) unsigned short A_lds[128 * 128];
    __shared__ __align__(16) unsigned short W_lds[128 * 128];

    const int tid = threadIdx.x;
    const int m0 = blockIdx.x * 128;
    const int w = tid >> 6, lane = tid & 63, g = lane >> 4, m = lane & 15;
    const int wr = w >> 1, wc = w & 1;

    #pragma unroll
    for (int it = 0; it < 8; ++it) {
        int idx = it * 256 + tid;
        int row = idx >> 4, c8 = idx & 15;
        short8 av = *(const short8*)(A + (size_t)(m0 + row) * 128 + c8 * 8);
        int off = (row * 256 + c8 * 16) ^ ((row & 7) << 4);
        *(short8*)((char*)A_lds + off) = av;
    }

    unsigned short* outp[4] = {qh, kh, vh, gh};
    for (int wsel = 0; wsel < 4; ++wsel) {
        __syncthreads();   // also covers A-stage on first iteration
        #pragma unroll
        for (int it = 0; it < 8; ++it) {
            int idx = it * 256 + tid;
            int row = idx >> 4, c8 = idx & 15;
            short8 wv = *(const short8*)(wt + wsel * 16384 + row * 128 + c8 * 8);
            int off = (row * 256 + c8 * 16) ^ ((row & 7) << 4);
            *(short8*)((char*)W_lds + off) = wv;
        }
        __syncthreads();

        f32x4 acc[4][4];
        #pragma unroll
        for (int mt = 0; mt < 4; ++mt)
            #pragma unroll
            for (int nt = 0; nt < 4; ++nt) acc[mt][nt] = (f32x4){0.f,0.f,0.f,0.f};

        #pragma unroll
        for (int kc = 0; kc < 4; ++kc) {
            short8 a[4], b[4];
            #pragma unroll
            for (int mt = 0; mt < 4; ++mt) {
                int row = wr * 64 + mt * 16 + m;
                a[mt] = *(const short8*)((const char*)A_lds +
                         ((row * 256 + kc * 64 + 16 * g) ^ ((row & 7) << 4)));
            }
            #pragma unroll
            for (int nt = 0; nt < 4; ++nt) {
                int row = wc * 64 + nt * 16 + m;
                b[nt] = *(const short8*)((const char*)W_lds +
                         ((row * 256 + kc * 64 + 16 * g) ^ ((row & 7) << 4)));
            }
            #pragma unroll
            for (int mt = 0; mt < 4; ++mt)
                #pragma unroll
                for (int nt = 0; nt < 4; ++nt)
                    acc[mt][nt] = __builtin_amdgcn_mfma_f32_16x16x32_bf16(
                                      b[nt], a[mt], acc[mt][nt], 0, 0, 0);
        }

        #pragma unroll
        for (int nt = 0; nt < 4; ++nt) {
            int col = wc * 64 + nt * 16 + 4 * g;
            int hsel = col >> 5, c32 = col & 31;
            unsigned short* OB = outp[wsel] + (size_t)hsel * HSTRIDE;
            float4 bv = make_float4(0.f,0.f,0.f,0.f);
            if (wsel == 3) bv = *(const float4*)(g_b + col);
            #pragma unroll
            for (int mt = 0; mt < 4; ++mt) {
                int row = m0 + wr * 64 + mt * 16 + m;
                float v0 = acc[mt][nt][0], v1 = acc[mt][nt][1];
                float v2 = acc[mt][nt][2], v3 = acc[mt][nt][3];
                if (wsel == 3) {
                    v0 = 1.0f / (1.0f + __expf(-(v0 + bv.x)));
                    v1 = 1.0f / (1.0f + __expf(-(v1 + bv.y)));
                    v2 = 1.0f / (1.0f + __expf(-(v2 + bv.z)));
                    v3 = 1.0f / (1.0f + __expf(-(v3 + bv.w)));
                }
                ushort4 o;
                o.x = f2bf(v0); o.y = f2bf(v1); o.z = f2bf(v2); o.w = f2bf(v3);
                *(ushort4*)(OB + (size_t)row * 32 + c32) = o;
            }
        }
    }
}

// ---------------------------------------------------------------------------
// Output projection: out[M,128] = og @ o_w + o_b (f32 out), og head-separated.
// ---------------------------------------------------------------------------
__global__ __launch_bounds__(256) void oproj_kernel(
    const unsigned short* __restrict__ ogh, const unsigned short* __restrict__ Wt,
    const float* __restrict__ bias, float* __restrict__ out)
{
    __shared__ __align__(16) unsigned short A_lds[128 * 128];
    __shared__ __align__(16) unsigned short W_lds[128 * 128];

    const int tid = threadIdx.x;
    const int m0 = blockIdx.x * 128;
    const int w = tid >> 6, lane = tid & 63, g = lane >> 4, m = lane & 15;
    const int wr = w >> 1, wc = w & 1;

    #pragma unroll
    for (int it = 0; it < 8; ++it) {
        int idx = it * 256 + tid;
        int row = idx >> 4, c8 = idx & 15;
        short8 av = *(const short8*)(ogh + (size_t)(c8 >> 2) * HSTRIDE
                                     + (size_t)(m0 + row) * 32 + (c8 & 3) * 8);
        short8 wv = *(const short8*)(Wt + row * 128 + c8 * 8);
        int off = (row * 256 + c8 * 16) ^ ((row & 7) << 4);
        *(short8*)((char*)A_lds + off) = av;
        *(short8*)((char*)W_lds + off) = wv;
    }
    __syncthreads();

    f32x4 acc[4][4];
    #pragma unroll
    for (int mt = 0; mt < 4; ++mt)
        #pragma unroll
        for (int nt = 0; nt < 4; ++nt) acc[mt][nt] = (f32x4){0.f,0.f,0.f,0.f};

    #pragma unroll
    for (int kc = 0; kc < 4; ++kc) {
        short8 a[4], b[4];
        #pragma unroll
        for (int mt = 0; mt < 4; ++mt) {
            int row = wr * 64 + mt * 16 + m;
            a[mt] = *(const short8*)((const char*)A_lds +
                     ((row * 256 + kc * 64 + 16 * g) ^ ((row & 7) << 4)));
        }
        #pragma unroll
        for (int nt = 0; nt < 4; ++nt) {
            int row = wc * 64 + nt * 16 + m;
            b[nt] = *(const short8*)((const char*)W_lds +
                     ((row * 256 + kc * 64 + 16 * g) ^ ((row & 7) << 4)));
        }
        #pragma unroll
        for (int mt = 0; mt < 4; ++mt)
            #pragma unroll
            for (int nt = 0; nt < 4; ++nt)
                acc[mt][nt] = __builtin_amdgcn_mfma_f32_16x16x32_bf16(
                                  b[nt], a[mt], acc[mt][nt], 0, 0, 0);
    }

    #pragma unroll
    for (int nt = 0; nt < 4; ++nt) {
        int col = wc * 64 + nt * 16 + 4 * g;
        float4 bv = *(const float4*)(bias + col);
        #pragma unroll
        for (int mt = 0; mt < 4; ++mt) {
            int row = m0 + wr * 64 + mt * 16 + m;
            float4 o;
            o.x = acc[mt][nt][0] + bv.x;
            o.y = acc[mt][nt][1] + bv.y;
            o.z = acc[mt][nt][2] + bv.z;
            o.w = acc[mt][nt][3] + bv.w;
            *(float4*)(out + (size_t)row * 128 + col) = o;
        }
    }
}

// ---------------------------------------------------------------------------
// MFMA attention, block per (i,h). Head-separated I/O (contiguous 16 KB
// slices), tiled tri reads (contiguous 512B per wave), no max-subtraction,
// P exchange in-register via ds_bpermute (parity-relabeled slots).
// ---------------------------------------------------------------------------
__global__ __launch_bounds__(256, 3) void attn_kernel(
    const unsigned short* __restrict__ qh, const unsigned short* __restrict__ kh,
    const unsigned short* __restrict__ vh, const unsigned short* __restrict__ gh,
    const float* __restrict__ mask, const unsigned short* __restrict__ triT,
    unsigned short* __restrict__ ogh)
{
    __shared__ __align__(16) unsigned short K_lds[256 * 40];   // 80B rows
    __shared__ __align__(16) unsigned short Vc[32 * 264];      // col-major, pad
    __shared__ float mb[256];

    const int i = blockIdx.x, h = blockIdx.y;
    const int tid = threadIdx.x;
    const int w = tid >> 6, lane = tid & 63, g = lane >> 4, m = lane & 15;
    const size_t hb = (size_t)h * HSTRIDE + (size_t)i * 8192;   // [h][i*256][32]

    #pragma unroll
    for (int it = 0; it < 4; ++it) {
        int idx = it * 256 + tid;
        int j = idx >> 2, d0 = (idx & 3) * 8;
        short8 kv = *(const short8*)(kh + hb + (size_t)j * 32 + d0);
        short8 vv = *(const short8*)(vh + hb + (size_t)j * 32 + d0);
        *(short8*)((char*)K_lds + j * 80 + d0 * 2) = kv;
        unsigned short* vp = (unsigned short*)&vv;
        #pragma unroll
        for (int e = 0; e < 8; ++e) Vc[(d0 + e) * 264 + j] = vp[e];
    }
    mb[tid] = (mask[i * 256 + tid] - 1.0f) * (1.0e9f * LOG2E_);
    __syncthreads();

    // bpermute lane indices: classA srcs [0,2,1,3], classB = srcA^1
    const int srcA = ((g & 1) << 1) | (g >> 1);
    const int idxA = (srcA * 16 + m) * 4;
    const int idxB = idxA ^ 64;
    const bool low = (lane < 32);
    const bool odd = (g & 1);
    const char* VcB0 = (const char*)Vc + m * 528;
    const char* VcB1 = (const char*)Vc + (16 + m) * 528;
    const f32x4 zero = {0.f, 0.f, 0.f, 0.f};
    // tiled tri base for this lane: + qt*4096 + kt*256 at use
    const unsigned short* triL = triT + h * 65536 + m * 16 + 4 * g;

    #pragma unroll 1
    for (int t = 0; t < 4; ++t) {
        const int qrow = w * 64 + t * 16 + m;
        const short8 qf = *(const short8*)(qh + hb + (size_t)qrow * 32 + 8 * g);
        const unsigned short* triQ = triL + (w * 4 + t) * 4096;

        int pk[32];
        float ls = 0.f;

        #pragma unroll
        for (int ktp = 0; ktp < 8; ++ktp) {
            int d00, d01, d10, d11;
            {
                const int kt = 2 * ktp;
                short8 af = *(const short8*)((const char*)K_lds + (kt * 16 + m) * 80 + 16 * g);
                f32x4 acc = __builtin_amdgcn_mfma_f32_16x16x32_bf16(af, qf, zero, 0, 0, 0);
                f32x4 mbv = *(const f32x4*)(mb + kt * 16 + 4 * g);
                int2 td = *(const int2*)(triQ + kt * 256);
                float t0 = __uint_as_float((unsigned)td.x << 16);
                float t1 = __uint_as_float((unsigned)td.x & 0xffff0000u);
                float t2 = __uint_as_float((unsigned)td.y << 16);
                float t3 = __uint_as_float((unsigned)td.y & 0xffff0000u);
                float p0 = EXP2F(acc[0] + mbv[0] + t0);
                float p1 = EXP2F(acc[1] + mbv[1] + t1);
                float p2 = EXP2F(acc[2] + mbv[2] + t2);
                float p3 = EXP2F(acc[3] + mbv[3] + t3);
                ls += (p0 + p1) + (p2 + p3);
                d00 = pk2bf(p0, p1); d01 = pk2bf(p2, p3);
            }
            {
                const int kt = 2 * ktp + 1;
                short8 af = *(const short8*)((const char*)K_lds + (kt * 16 + m) * 80 + 16 * g);
                f32x4 acc = __builtin_amdgcn_mfma_f32_16x16x32_bf16(af, qf, zero, 0, 0, 0);
                f32x4 mbv = *(const f32x4*)(mb + kt * 16 + 4 * g);
                int2 td = *(const int2*)(triQ + kt * 256);
                float t0 = __uint_as_float((unsigned)td.x << 16);
                float t1 = __uint_as_float((unsigned)td.x & 0xffff0000u);
                float t2 = __uint_as_float((unsigned)td.y << 16);
                float t3 = __uint_as_float((unsigned)td.y & 0xffff0000u);
                float p0 = EXP2F(acc[0] + mbv[0] + t0);
                float p1 = EXP2F(acc[1] + mbv[1] + t1);
                float p2 = EXP2F(acc[2] + mbv[2] + t2);
                float p3 = EXP2F(acc[3] + mbv[3] + t3);
                ls += (p0 + p1) + (p2 + p3);
                d10 = pk2bf(p0, p1); d11 = pk2bf(p2, p3);
            }
            // parity relabel: odd g-groups store kt^1 in the kt slot-pair
            pk[4 * ktp + 0] = odd ? d10 : d00;
            pk[4 * ktp + 1] = odd ? d11 : d01;
            pk[4 * ktp + 2] = odd ? d00 : d10;
            pk[4 * ktp + 3] = odd ? d01 : d11;
        }
        ls += __shfl_xor(ls, 16, 64);
        ls += __shfl_xor(ls, 32, 64);

        f32x4 o0 = zero, o1 = zero;
        #pragma unroll
        for (int c = 0; c < 8; ++c) {
            int dA0 = __builtin_amdgcn_ds_bpermute(idxA, pk[4 * c + 0]);
            int dA1 = __builtin_amdgcn_ds_bpermute(idxA, pk[4 * c + 1]);
            int dB0 = __builtin_amdgcn_ds_bpermute(idxB, pk[4 * c + 2]);
            int dB1 = __builtin_amdgcn_ds_bpermute(idxB, pk[4 * c + 3]);
            union { int4 i4; short8 s8; } bu;
            bu.i4.x = low ? dA0 : dB0;
            bu.i4.y = low ? dA1 : dB1;
            bu.i4.z = low ? dB0 : dA0;
            bu.i4.w = low ? dB1 : dA1;
            short8 av0 = *(const short8*)(VcB0 + c * 64 + 16 * g);
            short8 av1 = *(const short8*)(VcB1 + c * 64 + 16 * g);
            o0 = __builtin_amdgcn_mfma_f32_16x16x32_bf16(av0, bu.s8, o0, 0, 0, 0);
            o1 = __builtin_amdgcn_mfma_f32_16x16x32_bf16(av1, bu.s8, o1, 0, 0, 0);
        }

        float inv = 1.0f / ls;
        size_t ro = hb + (size_t)qrow * 32;
        ushort4 g0 = *(const ushort4*)(gh + ro + 4 * g);
        ushort4 g1 = *(const ushort4*)(gh + ro + 16 + 4 * g);
        ushort4 s0, s1;
        s0.x = f2bf(o0[0] * inv * bf2f(g0.x));
        s0.y = f2bf(o0[1] * inv * bf2f(g0.y));
        s0.z = f2bf(o0[2] * inv * bf2f(g0.z));
        s0.w = f2bf(o0[3] * inv * bf2f(g0.w));
        s1.x = f2bf(o1[0] * inv * bf2f(g1.x));
        s1.y = f2bf(o1[1] * inv * bf2f(g1.y));
        s1.z = f2bf(o1[2] * inv * bf2f(g1.z));
        s1.w = f2bf(o1[3] * inv * bf2f(g1.w));
        *(ushort4*)(ogh + ro + 4 * g) = s0;
        *(ushort4*)(ogh + ro + 16 + 4 * g) = s1;
    }
}

// ---------------------------------------------------------------------------
extern "C" void kernel_launch(void* const* d_in, const int* in_sizes, int n_in,
                              void* d_out, int out_size, void* d_ws, size_t ws_size,
                              hipStream_t stream) {
    (void)in_sizes; (void)n_in; (void)out_size; (void)ws_size;
    const float* x    = (const float*)d_in[0];
    const float* mask = (const float*)d_in[1];
    const float* ln_w = (const float*)d_in[2];
    const float* ln_b = (const float*)d_in[3];
    const float* tri_w= (const float*)d_in[4];
    const float* q_w  = (const float*)d_in[5];
    const float* k_w  = (const float*)d_in[6];
    const float* v_w  = (const float*)d_in[7];
    const float* g_w  = (const float*)d_in[8];
    const float* g_b  = (const float*)d_in[9];
    const float* o_w  = (const float*)d_in[10];
    const float* o_b  = (const float*)d_in[11];

    char* ws = (char*)d_ws;
    unsigned short* xn  = (unsigned short*)(ws);                 // 16 MB
    unsigned short* qhp = (unsigned short*)(ws + 16777216);      // [4][65536][32]
    unsigned short* khp = (unsigned short*)(ws + 33554432);
    unsigned short* vhp = (unsigned short*)(ws + 50331648);
    unsigned short* ghp = (unsigned short*)(ws + 67108864);
    unsigned short* ogh = (unsigned short*)(ws + 83886080);
    unsigned short* tri = (unsigned short*)(ws + 100663296);     // 512 KB tiled
    unsigned short* wt  = (unsigned short*)(ws + 101711872);     // 160 KB

    prep_w_kernel<<<320, 256, 0, stream>>>(q_w, k_w, v_w, g_w, o_w, wt);
    ln_tri_kernel<<<16384, 256, 0, stream>>>(x, ln_w, ln_b, tri_w, xn, tri);

    proj4_kernel<<<512, 256, 0, stream>>>(xn, wt, g_b, qhp, khp, vhp, ghp);

    dim3 ga(256, 4);
    attn_kernel<<<ga, 256, 0, stream>>>(qhp, khp, vhp, ghp, mask, tri, ogh);

    oproj_kernel<<<512, 256, 0, stream>>>(ogh, wt + 65536, o_b, (float*)d_out);
}